// Round 4
// baseline (729.873 us; speedup 1.0000x reference)
//
#include <hip/hip_runtime.h>
#include <hip/hip_bf16.h>

typedef __bf16 bf16x8_t __attribute__((ext_vector_type(8)));
typedef float f32x4_t __attribute__((ext_vector_type(4)));

#define B_ 2
#define T_ 2048
#define D_ 1024
#define DC_ 512
#define DM_ 1536
#define H_ 16
#define DE_ 4096
#define DG_ 1024
#define ROWS (B_*T_)   // 4096
#define QS_ 2560       // fused q|k|v row stride
#define MB (1u<<20)

#define GPTR(p) ((const __attribute__((address_space(1))) unsigned int*)(p))
#define LPTR(p) ((__attribute__((address_space(3))) unsigned int*)(p))

__device__ __forceinline__ float sigmoid_f(float x) { return 1.f / (1.f + __expf(-x)); }

// ---------------------------------------------------------------------------
// Weight transpose + cast: W[K,N] fp32 -> Wt[N,K] bf16
// ---------------------------------------------------------------------------
__global__ __launch_bounds__(256)
void transpose_cast(const float* __restrict__ W, __hip_bfloat16* __restrict__ Wt,
                    int K, int N) {
    __shared__ float t[32][33];
    const int n0 = blockIdx.x * 32, k0 = blockIdx.y * 32;
    const int tx = threadIdx.x, ty = threadIdx.y;
#pragma unroll
    for (int r = 0; r < 4; ++r)
        t[ty + r * 8][tx] = W[(size_t)(k0 + ty + r * 8) * N + n0 + tx];
    __syncthreads();
#pragma unroll
    for (int r = 0; r < 4; ++r)
        Wt[(size_t)(n0 + ty + r * 8) * K + k0 + tx] = __float2bfloat16(t[tx][ty + r * 8]);
}

// ---------------------------------------------------------------------------
// bqkv = concat(bq, bk, bv)
// ---------------------------------------------------------------------------
__global__ __launch_bounds__(256)
void concat_bias(const float* __restrict__ bq, const float* __restrict__ bk,
                 const float* __restrict__ bv, float* __restrict__ o) {
    const int i = blockIdx.x * 256 + threadIdx.x;
    if (i < QS_)
        o[i] = i < 512 ? bq[i] : (i < 1024 ? bk[i - 512] : bv[i - 1024]);
}

// ---------------------------------------------------------------------------
// V transpose out of fused qkv: QKV[b*T+t][1024 + h*96 + d] -> Vt[(bh*96+d)][t]
// ---------------------------------------------------------------------------
__global__ __launch_bounds__(256)
void transpose_v(const __hip_bfloat16* __restrict__ QKV, __hip_bfloat16* __restrict__ Vt) {
    __shared__ __hip_bfloat16 t[32][33];
    const int bh = blockIdx.z;
    const int b = bh >> 4, h = bh & 15;
    const int t0 = blockIdx.x * 32;   // T dim
    const int d0 = blockIdx.y * 32;   // head dim (0..95)
    const int tx = threadIdx.x, ty = threadIdx.y;  // (32,8)
#pragma unroll
    for (int r = 0; r < 4; ++r)
        t[ty + r * 8][tx] = QKV[(size_t)(b * T_ + t0 + ty + r * 8) * QS_ + 1024 + h * 96 + d0 + tx];
    __syncthreads();
#pragma unroll
    for (int r = 0; r < 4; ++r)
        Vt[((size_t)bh * 96 + d0 + ty + r * 8) * T_ + t0 + tx] = t[tx][ty + r * 8];
}

// ---------------------------------------------------------------------------
// LayerNorm over D=1024, fp32 in -> bf16 out. One block (256 thr) per row.
// ---------------------------------------------------------------------------
__global__ __launch_bounds__(256)
void ln_cast(const float* __restrict__ x, const float* __restrict__ w,
             const float* __restrict__ b, __hip_bfloat16* __restrict__ out) {
    const int row = blockIdx.x;
    const int tid = threadIdx.x;
    const float4 v = ((const float4*)(x + (size_t)row * D_))[tid];
    float s = v.x + v.y + v.z + v.w;
#pragma unroll
    for (int o = 32; o; o >>= 1) s += __shfl_down(s, o);
    __shared__ float red1[4], red2[4];
    if (!(tid & 63)) red1[tid >> 6] = s;
    __syncthreads();
    const float mu = (red1[0] + red1[1] + red1[2] + red1[3]) * (1.f / D_);
    const float dx = v.x - mu, dy = v.y - mu, dz = v.z - mu, dw = v.w - mu;
    float s2 = dx * dx + dy * dy + dz * dz + dw * dw;
#pragma unroll
    for (int o = 32; o; o >>= 1) s2 += __shfl_down(s2, o);
    if (!(tid & 63)) red2[tid >> 6] = s2;
    __syncthreads();
    const float var = (red2[0] + red2[1] + red2[2] + red2[3]) * (1.f / D_);
    const float rs = rsqrtf(var + 1e-5f);
    const float4 wv = ((const float4*)w)[tid];
    const float4 bv = ((const float4*)b)[tid];
    __hip_bfloat16* op = out + (size_t)row * D_ + tid * 4;
    op[0] = __float2bfloat16(dx * rs * wv.x + bv.x);
    op[1] = __float2bfloat16(dy * rs * wv.y + bv.y);
    op[2] = __float2bfloat16(dz * rs * wv.z + bv.z);
    op[3] = __float2bfloat16(dw * rs * wv.w + bv.w);
}

// ---------------------------------------------------------------------------
// bf16 MFMA GEMM, global_load_lds staging. C[M,N] = A[M,K] @ Bt[N,K]^T + bias.
// EPI 0: bf16;  1: fp32 = resid + v;  2: bf16 = silu(v);
// EPI 4: bf16 = silu(Ein * sigmoid(v))  (Ein may alias Cout)
// Staging lane map: wave-uniform k-chunk c, lane-consecutive rows -> LDS dest
// is wave base + lane*16 (required by global_load_lds).
// ---------------------------------------------------------------------------
template <int EPI>
__global__ __launch_bounds__(256)
void gemm_bt(const __hip_bfloat16* __restrict__ A, const __hip_bfloat16* __restrict__ Bt,
             const float* __restrict__ bias, const float* __restrict__ resid,
             const __hip_bfloat16* __restrict__ Ein,
             void* __restrict__ Cout, int M, int N, int K) {
    __shared__ __hip_bfloat16 As[4][128][8];
    __shared__ __hip_bfloat16 Bs[4][128][8];
    const int tid = threadIdx.x;
    const int m0 = blockIdx.y * 128;
    const int n0 = blockIdx.x * 128;
    const int lane = tid & 63;
    const int wave = tid >> 6;
    const int wm = (wave >> 1) * 64, wn = (wave & 1) * 64;
    const int kc = lane >> 4;
    const int lr = lane & 15;

    f32x4_t acc[4][4] = {};

    for (int k0 = 0; k0 < K; k0 += 32) {
#pragma unroll
        for (int p = 0; p < 2; ++p) {
            const int s = p * 256 + tid;   // 0..511
            const int c = s >> 7;          // wave-uniform
            const int row = s & 127;       // lane-consecutive
            __builtin_amdgcn_global_load_lds(
                GPTR(A + (size_t)(m0 + row) * K + k0 + c * 8),
                LPTR(&As[c][row][0]), 16, 0, 0);
            __builtin_amdgcn_global_load_lds(
                GPTR(Bt + (size_t)(n0 + row) * K + k0 + c * 8),
                LPTR(&Bs[c][row][0]), 16, 0, 0);
        }
        __syncthreads();
        bf16x8_t af[4], bfr[4];
#pragma unroll
        for (int i = 0; i < 4; ++i) af[i] = *(const bf16x8_t*)(&As[kc][wm + i * 16 + lr][0]);
#pragma unroll
        for (int j = 0; j < 4; ++j) bfr[j] = *(const bf16x8_t*)(&Bs[kc][wn + j * 16 + lr][0]);
#pragma unroll
        for (int i = 0; i < 4; ++i)
#pragma unroll
            for (int j = 0; j < 4; ++j)
                acc[i][j] = __builtin_amdgcn_mfma_f32_16x16x32_bf16(af[i], bfr[j], acc[i][j], 0, 0, 0);
        __syncthreads();
    }

    const int rbase = kc * 4;
#pragma unroll
    for (int j = 0; j < 4; ++j) {
        const int col = n0 + wn + j * 16 + lr;
        const float bj = bias[col];
#pragma unroll
        for (int i = 0; i < 4; ++i) {
#pragma unroll
            for (int r = 0; r < 4; ++r) {
                const int row = m0 + wm + i * 16 + rbase + r;
                const size_t o = (size_t)row * N + col;
                const float v = acc[i][j][r] + bj;
                if (EPI == 0)      ((__hip_bfloat16*)Cout)[o] = __float2bfloat16(v);
                else if (EPI == 1) ((float*)Cout)[o] = resid[o] + v;
                else if (EPI == 2) ((__hip_bfloat16*)Cout)[o] = __float2bfloat16(v * sigmoid_f(v));
                else {  // EPI 4
                    const float z = __bfloat162float(Ein[o]) * sigmoid_f(v);
                    ((__hip_bfloat16*)Cout)[o] = __float2bfloat16(z * sigmoid_f(z));
                }
            }
        }
    }
}

// ---------------------------------------------------------------------------
// MFMA flash attention. Grid (16, B*H); block processes q-tiles j and 31-j
// (triangular pairing -> exactly 17 K-iterations per block). K-tile = 128
// cols per iteration; softmax in log2 domain (exp2f).
// ---------------------------------------------------------------------------
__global__ __launch_bounds__(256)
void attn_mfma(const __hip_bfloat16* __restrict__ QKV, const __hip_bfloat16* __restrict__ Vt,
               __hip_bfloat16* __restrict__ Y) {
    __shared__ __hip_bfloat16 Ks[128][40];     // 128x32 data, pad rows to 80B
    __shared__ __hip_bfloat16 Vts[96][136];    // 96x128 data, pad rows to 272B
    __shared__ __hip_bfloat16 Ps[4][16][72];   // per-wave 16x64 P half-tile
    const int tid = threadIdx.x;
    const int lane = tid & 63;
    const int w = tid >> 6;
    const int c = lane & 15;
    const int quad = lane >> 4;
    const int bh = blockIdx.y;
    const int b = bh >> 4, h = bh & 15;
    const size_t qbase = (size_t)b * T_ * QS_ + h * 32;
    const size_t kbase = qbase + 512;
    const size_t vtbase = (size_t)bh * 96 * T_;
    const size_t ybase = (size_t)b * T_ * DM_ + h * 96;
    const float scale2 = 0.17677669529663687f * 1.4426950408889634f;  // /sqrt(32) * log2(e)

    for (int half = 0; half < 2; ++half) {
        const int qt = half ? (31 - (int)blockIdx.x) : (int)blockIdx.x;
        const int q0 = qt * 64;
        const int ntiles = (qt >> 1) + 1;
        const int qrow_a = q0 + w * 16 + c;
        const bf16x8_t qf = *(const bf16x8_t*)(QKV + qbase + (size_t)qrow_a * QS_ + quad * 8);

        f32x4_t o[6] = {};
        float mrow[4], lrow[4];
#pragma unroll
        for (int r = 0; r < 4; ++r) { mrow[r] = -1e30f; lrow[r] = 0.f; }
        const int row_c = q0 + w * 16 + quad * 4;

        for (int t = 0; t < ntiles; ++t) {
            const int k0 = t * 128;
            // stage K (128x32 = 8KB): 2 x 16B/thread
#pragma unroll
            for (int p = 0; p < 2; ++p) {
                const int idx = p * 256 + tid;
                const int kr = idx >> 2, cc = idx & 3;
                *(uint4*)(&Ks[kr][cc * 8]) =
                    *(const uint4*)(QKV + kbase + (size_t)(k0 + kr) * QS_ + cc * 8);
            }
            // stage Vt (96x128 = 24KB): 6 x 16B/thread
#pragma unroll
            for (int p = 0; p < 6; ++p) {
                const int idx = p * 256 + tid;
                const int vr = idx >> 4, vc = idx & 15;
                *(uint4*)(&Vts[vr][vc * 8]) =
                    *(const uint4*)(Vt + vtbase + (size_t)vr * T_ + k0 + vc * 8);
            }
            __syncthreads();

            // S = Q K^T : 8 MFMA per wave (16 rows x 128 cols)
            f32x4_t s[8];
#pragma unroll
            for (int t2 = 0; t2 < 8; ++t2) {
                const bf16x8_t kf = *(const bf16x8_t*)(&Ks[t2 * 16 + c][quad * 8]);
                f32x4_t z = {0.f, 0.f, 0.f, 0.f};
                s[t2] = __builtin_amdgcn_mfma_f32_16x16x32_bf16(qf, kf, z, 0, 0, 0);
            }

            float p[8][4];
            const bool needmask = (k0 + 128 > q0);   // uniform per iteration
            if (needmask) {
#pragma unroll
                for (int t2 = 0; t2 < 8; ++t2) {
                    const int col = k0 + t2 * 16 + c;
#pragma unroll
                    for (int r = 0; r < 4; ++r) {
                        float v = s[t2][r] * scale2;
                        if (col > row_c + r) v = -1e30f;
                        p[t2][r] = v;
                    }
                }
            } else {
#pragma unroll
                for (int t2 = 0; t2 < 8; ++t2)
#pragma unroll
                    for (int r = 0; r < 4; ++r) p[t2][r] = s[t2][r] * scale2;
            }

            // online softmax (log2 domain), rows live in 16-lane quad groups
#pragma unroll
            for (int r = 0; r < 4; ++r) {
                float mx = p[0][r];
#pragma unroll
                for (int t2 = 1; t2 < 8; ++t2) mx = fmaxf(mx, p[t2][r]);
#pragma unroll
                for (int o2 = 1; o2 < 16; o2 <<= 1) mx = fmaxf(mx, __shfl_xor(mx, o2));
                const float mnew = fmaxf(mrow[r], mx);
                const float alpha = exp2f(mrow[r] - mnew);
                mrow[r] = mnew;
                float rsum = 0.f;
#pragma unroll
                for (int t2 = 0; t2 < 8; ++t2) {
                    p[t2][r] = exp2f(p[t2][r] - mnew);
                    rsum += p[t2][r];
                }
#pragma unroll
                for (int o2 = 1; o2 < 16; o2 <<= 1) rsum += __shfl_xor(rsum, o2);
                lrow[r] = lrow[r] * alpha + rsum;
#pragma unroll
                for (int nb = 0; nb < 6; ++nb) o[nb][r] *= alpha;
            }

            // PV in two 64-col halves: P regs -> per-wave LDS -> A-frags
#pragma unroll
            for (int hh = 0; hh < 2; ++hh) {
#pragma unroll
                for (int t2 = 0; t2 < 4; ++t2)
#pragma unroll
                    for (int r = 0; r < 4; ++r)
                        Ps[w][quad * 4 + r][t2 * 16 + c] = __float2bfloat16(p[hh * 4 + t2][r]);
                const bf16x8_t pf0 = *(const bf16x8_t*)(&Ps[w][c][quad * 8]);
                const bf16x8_t pf1 = *(const bf16x8_t*)(&Ps[w][c][32 + quad * 8]);
#pragma unroll
                for (int nb = 0; nb < 6; ++nb) {
                    const bf16x8_t vf0 = *(const bf16x8_t*)(&Vts[nb * 16 + c][hh * 64 + quad * 8]);
                    o[nb] = __builtin_amdgcn_mfma_f32_16x16x32_bf16(pf0, vf0, o[nb], 0, 0, 0);
                    const bf16x8_t vf1 = *(const bf16x8_t*)(&Vts[nb * 16 + c][hh * 64 + 32 + quad * 8]);
                    o[nb] = __builtin_amdgcn_mfma_f32_16x16x32_bf16(pf1, vf1, o[nb], 0, 0, 0);
                }
            }
            __syncthreads();
        }

#pragma unroll
        for (int r = 0; r < 4; ++r) {
            const float inv = 1.f / lrow[r];
            const size_t rowoff = ybase + (size_t)(row_c + r) * DM_;
#pragma unroll
            for (int nb = 0; nb < 6; ++nb)
                Y[rowoff + nb * 16 + c] = __float2bfloat16(o[nb][r] * inv);
        }
    }
}

// ---------------------------------------------------------------------------
// Workspace map (99 MB; phase-aliased, lifetimes stream-ordered):
//   [  0,  5) wqkvT (wq|wk|wv contiguous along N)   [ 5, 8) woT
//   [  8, 16) weT   [16,18) wgT   [18,26) wuT   [26,34) wcT
//   [ 34,   ) bqkv fp32[2560]
//   [ 35, 43) x1b -> x2b
//   [ 43, 63) qkv  -> xmid fp32 (43..59) after attn consumes qkv
//   [ 63, 75) vt
//   [ 75, 87) yb
//   [ 59, 91) eb (after vt/yb dead; in-place EPI4)
//   [ 91, 99) hb
// ---------------------------------------------------------------------------
extern "C" void kernel_launch(void* const* d_in, const int* in_sizes, int n_in,
                              void* d_out, int out_size, void* d_ws, size_t ws_size,
                              hipStream_t stream) {
    const float* x     = (const float*)d_in[0];
    const float* ln1_w = (const float*)d_in[2];
    const float* ln1_b = (const float*)d_in[3];
    const float* wq = (const float*)d_in[4];  const float* bq = (const float*)d_in[5];
    const float* wk = (const float*)d_in[6];  const float* bk = (const float*)d_in[7];
    const float* wv = (const float*)d_in[8];  const float* bv = (const float*)d_in[9];
    const float* wo = (const float*)d_in[10]; const float* bo = (const float*)d_in[11];
    const float* ln2_w = (const float*)d_in[12];
    const float* ln2_b = (const float*)d_in[13];
    const float* we = (const float*)d_in[14]; const float* be = (const float*)d_in[15];
    const float* wg = (const float*)d_in[16]; const float* bg = (const float*)d_in[17];
    const float* wu = (const float*)d_in[18]; const float* bu = (const float*)d_in[19];
    const float* wc = (const float*)d_in[20]; const float* bc = (const float*)d_in[21];
    float* out = (float*)d_out;

    char* ws = (char*)d_ws;
    typedef __hip_bfloat16 bf16;
    bf16* wqkvT = (bf16*)(ws + (size_t) 0 * MB);
    bf16* wqT   = wqkvT;                          // [0,1)
    bf16* wkT   = (bf16*)(ws + (size_t) 1 * MB);  // [1,2)
    bf16* wvT   = (bf16*)(ws + (size_t) 2 * MB);  // [2,5)
    bf16* woT   = (bf16*)(ws + (size_t) 5 * MB);
    bf16* weT   = (bf16*)(ws + (size_t) 8 * MB);
    bf16* wgT   = (bf16*)(ws + (size_t)16 * MB);
    bf16* wuT   = (bf16*)(ws + (size_t)18 * MB);
    bf16* wcT   = (bf16*)(ws + (size_t)26 * MB);
    float* bqkv = (float*)(ws + (size_t)34 * MB);
    bf16* x1b   = (bf16*)(ws + (size_t)35 * MB);  // later x2b
    bf16* x2b   = x1b;
    bf16* qkv   = (bf16*)(ws + (size_t)43 * MB);  // 20MB; later xmid
    float* xmid = (float*)(ws + (size_t)43 * MB); // 16MB fp32
    bf16* vt    = (bf16*)(ws + (size_t)63 * MB);  // 12MB
    bf16* yb    = (bf16*)(ws + (size_t)75 * MB);  // 12MB
    bf16* eb    = (bf16*)(ws + (size_t)59 * MB);  // 32MB (vt/yb dead by then)
    bf16* hb    = (bf16*)(ws + (size_t)91 * MB);  // 8MB

    const dim3 tb(32, 8);
    transpose_cast<<<dim3(DC_ / 32, D_ / 32), tb, 0, stream>>>(wq, wqT, D_, DC_);
    transpose_cast<<<dim3(DC_ / 32, D_ / 32), tb, 0, stream>>>(wk, wkT, D_, DC_);
    transpose_cast<<<dim3(DM_ / 32, D_ / 32), tb, 0, stream>>>(wv, wvT, D_, DM_);
    transpose_cast<<<dim3(D_ / 32, DM_ / 32), tb, 0, stream>>>(wo, woT, DM_, D_);
    transpose_cast<<<dim3(DE_ / 32, D_ / 32), tb, 0, stream>>>(we, weT, D_, DE_);
    transpose_cast<<<dim3(DG_ / 32, D_ / 32), tb, 0, stream>>>(wg, wgT, D_, DG_);
    transpose_cast<<<dim3(DE_ / 32, DG_ / 32), tb, 0, stream>>>(wu, wuT, DG_, DE_);
    transpose_cast<<<dim3(D_ / 32, DE_ / 32), tb, 0, stream>>>(wc, wcT, DE_, D_);
    concat_bias<<<(QS_ + 255) / 256, 256, 0, stream>>>(bq, bk, bv, bqkv);

    ln_cast<<<ROWS, 256, 0, stream>>>(x, ln1_w, ln1_b, x1b);

    // fused q|k|v GEMM: N = 2560
    gemm_bt<0><<<dim3(QS_ / 128, ROWS / 128), 256, 0, stream>>>(x1b, wqkvT, bqkv, nullptr, nullptr, qkv, ROWS, QS_, D_);

    transpose_v<<<dim3(T_ / 32, 3, B_ * H_), tb, 0, stream>>>(qkv, vt);

    attn_mfma<<<dim3(16, B_ * H_), 256, 0, stream>>>(qkv, vt, yb);

    gemm_bt<1><<<dim3(D_ / 128, ROWS / 128), 256, 0, stream>>>(yb, woT, bo, x, nullptr, xmid, ROWS, D_, DM_);

    ln_cast<<<ROWS, 256, 0, stream>>>(xmid, ln2_w, ln2_b, x2b);

    gemm_bt<0><<<dim3(DE_ / 128, ROWS / 128), 256, 0, stream>>>(x2b, weT, be, nullptr, nullptr, eb, ROWS, DE_, D_);
    gemm_bt<2><<<dim3(DG_ / 128, ROWS / 128), 256, 0, stream>>>(x2b, wgT, bg, nullptr, nullptr, hb, ROWS, DG_, D_);
    gemm_bt<4><<<dim3(DE_ / 128, ROWS / 128), 256, 0, stream>>>(hb, wuT, bu, nullptr, eb, eb, ROWS, DE_, DG_);

    gemm_bt<1><<<dim3(D_ / 128, ROWS / 128), 256, 0, stream>>>(eb, wcT, bc, xmid, nullptr, out, ROWS, D_, DE_);
}

// Round 5
// 566.482 us; speedup vs baseline: 1.2884x; 1.2884x over previous
//
#include <hip/hip_runtime.h>
#include <hip/hip_bf16.h>

typedef __bf16 bf16x8_t __attribute__((ext_vector_type(8)));
typedef float f32x4_t __attribute__((ext_vector_type(4)));

#define B_ 2
#define T_ 2048
#define D_ 1024
#define DC_ 512
#define DM_ 1536
#define H_ 16
#define DE_ 4096
#define DG_ 1024
#define ROWS (B_*T_)   // 4096
#define QS_ 2560       // fused q|k|v row stride
#define EG_ 5120       // fused we|wg N
#define MB (1u<<20)

#define GPTR(p) ((const __attribute__((address_space(1))) unsigned int*)(p))
#define LPTR(p) ((__attribute__((address_space(3))) unsigned int*)(p))

__device__ __forceinline__ float sigmoid_f(float x) { return 1.f / (1.f + __expf(-x)); }

// ---------------------------------------------------------------------------
// Weight transpose + cast: W[K,N] fp32 -> Wt[N,K] bf16
// ---------------------------------------------------------------------------
__global__ __launch_bounds__(256)
void transpose_cast(const float* __restrict__ W, __hip_bfloat16* __restrict__ Wt,
                    int K, int N) {
    __shared__ float t[32][33];
    const int n0 = blockIdx.x * 32, k0 = blockIdx.y * 32;
    const int tx = threadIdx.x, ty = threadIdx.y;
#pragma unroll
    for (int r = 0; r < 4; ++r)
        t[ty + r * 8][tx] = W[(size_t)(k0 + ty + r * 8) * N + n0 + tx];
    __syncthreads();
#pragma unroll
    for (int r = 0; r < 4; ++r)
        Wt[(size_t)(n0 + ty + r * 8) * K + k0 + tx] = __float2bfloat16(t[tx][ty + r * 8]);
}

// ---------------------------------------------------------------------------
__global__ __launch_bounds__(256)
void concat_bias3(const float* __restrict__ a, int na, const float* __restrict__ b,
                  int nb, const float* __restrict__ c, int n, float* __restrict__ o) {
    const int i = blockIdx.x * 256 + threadIdx.x;
    if (i < n)
        o[i] = i < na ? a[i] : (i < na + nb ? b[i - na] : c[i - na - nb]);
}

// ---------------------------------------------------------------------------
// V transpose out of fused qkv: QKV[b*T+t][1024 + h*96 + d] -> Vt[(bh*96+d)][t]
// ---------------------------------------------------------------------------
__global__ __launch_bounds__(256)
void transpose_v(const __hip_bfloat16* __restrict__ QKV, __hip_bfloat16* __restrict__ Vt) {
    __shared__ __hip_bfloat16 t[32][33];
    const int bh = blockIdx.z;
    const int b = bh >> 4, h = bh & 15;
    const int t0 = blockIdx.x * 32;
    const int d0 = blockIdx.y * 32;
    const int tx = threadIdx.x, ty = threadIdx.y;  // (32,8)
#pragma unroll
    for (int r = 0; r < 4; ++r)
        t[ty + r * 8][tx] = QKV[(size_t)(b * T_ + t0 + ty + r * 8) * QS_ + 1024 + h * 96 + d0 + tx];
    __syncthreads();
#pragma unroll
    for (int r = 0; r < 4; ++r)
        Vt[((size_t)bh * 96 + d0 + ty + r * 8) * T_ + t0 + tx] = t[tx][ty + r * 8];
}

// ---------------------------------------------------------------------------
// LayerNorm over D=1024, fp32 in -> bf16 out. One block (256 thr) per row.
// ---------------------------------------------------------------------------
__global__ __launch_bounds__(256)
void ln_cast(const float* __restrict__ x, const float* __restrict__ w,
             const float* __restrict__ b, __hip_bfloat16* __restrict__ out) {
    const int row = blockIdx.x;
    const int tid = threadIdx.x;
    const float4 v = ((const float4*)(x + (size_t)row * D_))[tid];
    float s = v.x + v.y + v.z + v.w;
#pragma unroll
    for (int o = 32; o; o >>= 1) s += __shfl_down(s, o);
    __shared__ float red1[4], red2[4];
    if (!(tid & 63)) red1[tid >> 6] = s;
    __syncthreads();
    const float mu = (red1[0] + red1[1] + red1[2] + red1[3]) * (1.f / D_);
    const float dx = v.x - mu, dy = v.y - mu, dz = v.z - mu, dw = v.w - mu;
    float s2 = dx * dx + dy * dy + dz * dz + dw * dw;
#pragma unroll
    for (int o = 32; o; o >>= 1) s2 += __shfl_down(s2, o);
    if (!(tid & 63)) red2[tid >> 6] = s2;
    __syncthreads();
    const float var = (red2[0] + red2[1] + red2[2] + red2[3]) * (1.f / D_);
    const float rs = rsqrtf(var + 1e-5f);
    const float4 wv = ((const float4*)w)[tid];
    const float4 bv = ((const float4*)b)[tid];
    __hip_bfloat16* op = out + (size_t)row * D_ + tid * 4;
    op[0] = __float2bfloat16(dx * rs * wv.x + bv.x);
    op[1] = __float2bfloat16(dy * rs * wv.y + bv.y);
    op[2] = __float2bfloat16(dz * rs * wv.z + bv.z);
    op[3] = __float2bfloat16(dw * rs * wv.w + bv.w);
}

// ---------------------------------------------------------------------------
// bf16 MFMA GEMM, swizzled global_load_lds staging.
// LDS slot s (16B) holds chunk kc=(s&3)^((row>>1)&3) of row=s>>2:
//   - staging: 4 lanes/row fetch a permutation of the row's 4 chunks -> one
//     64B line per row, coalesced; dest = base + lane*16 as HW requires.
//   - frag read: slot=row*4+(quad^((row>>1)&3)) -> exactly 8 acc/bank (free).
// EPI 0: bf16;  1: fp32 = resid + v;  4: bf16 = silu(Ein*sigmoid(v)) in-place;
// EPI 5: col<DE -> C0 bf16 (stride DE), col>=DE -> C1 bf16 silu(v) (stride DG)
// ---------------------------------------------------------------------------
template <int EPI, int BM, int BN>
__global__ __launch_bounds__(256)
void gemm_bt(const __hip_bfloat16* __restrict__ A, const __hip_bfloat16* __restrict__ Bt,
             const float* __restrict__ bias, const float* __restrict__ resid,
             const __hip_bfloat16* __restrict__ Ein,
             void* __restrict__ C0, void* __restrict__ C1, int M, int N, int K) {
    __shared__ __align__(16) __hip_bfloat16 As[BM * 32];
    __shared__ __align__(16) __hip_bfloat16 Bs[BN * 32];
    const int tid = threadIdx.x;
    const int m0 = blockIdx.y * BM;
    const int n0 = blockIdx.x * BN;
    const int lane = tid & 63;
    const int wave = tid >> 6;
    const int wm = (wave >> 1) * (BM / 2), wn = (wave & 1) * (BN / 2);
    const int quad = lane >> 4;
    const int lr = lane & 15;
    constexpr int MI = BM / 32, NJ = BN / 32;

    f32x4_t acc[MI][NJ] = {};

    for (int k0 = 0; k0 < K; k0 += 32) {
#pragma unroll
        for (int p = 0; p < BM / 64; ++p) {
            const int s = p * 256 + tid;
            const int row = s >> 2;
            const int kc2 = (s & 3) ^ ((row >> 1) & 3);
            __builtin_amdgcn_global_load_lds(
                GPTR(A + (size_t)(m0 + row) * K + k0 + kc2 * 8),
                LPTR(&As[s * 8]), 16, 0, 0);
        }
#pragma unroll
        for (int p = 0; p < BN / 64; ++p) {
            const int s = p * 256 + tid;
            const int row = s >> 2;
            const int kc2 = (s & 3) ^ ((row >> 1) & 3);
            __builtin_amdgcn_global_load_lds(
                GPTR(Bt + (size_t)(n0 + row) * K + k0 + kc2 * 8),
                LPTR(&Bs[s * 8]), 16, 0, 0);
        }
        __syncthreads();
        bf16x8_t af[MI], bfr[NJ];
#pragma unroll
        for (int i = 0; i < MI; ++i) {
            const int row = wm + i * 16 + lr;
            af[i] = *(const bf16x8_t*)(&As[(row * 4 + (quad ^ ((row >> 1) & 3))) * 8]);
        }
#pragma unroll
        for (int j = 0; j < NJ; ++j) {
            const int row = wn + j * 16 + lr;
            bfr[j] = *(const bf16x8_t*)(&Bs[(row * 4 + (quad ^ ((row >> 1) & 3))) * 8]);
        }
#pragma unroll
        for (int i = 0; i < MI; ++i)
#pragma unroll
            for (int j = 0; j < NJ; ++j)
                acc[i][j] = __builtin_amdgcn_mfma_f32_16x16x32_bf16(af[i], bfr[j], acc[i][j], 0, 0, 0);
        __syncthreads();
    }

    const int rbase = quad * 4;
#pragma unroll
    for (int j = 0; j < NJ; ++j) {
        const int col = n0 + wn + j * 16 + lr;
        const float bj = bias[col];
#pragma unroll
        for (int i = 0; i < MI; ++i) {
#pragma unroll
            for (int r = 0; r < 4; ++r) {
                const int row = m0 + wm + i * 16 + rbase + r;
                const float v = acc[i][j][r] + bj;
                if (EPI == 0) {
                    ((__hip_bfloat16*)C0)[(size_t)row * N + col] = __float2bfloat16(v);
                } else if (EPI == 1) {
                    const size_t o = (size_t)row * N + col;
                    ((float*)C0)[o] = resid[o] + v;
                } else if (EPI == 4) {
                    const size_t o = (size_t)row * N + col;
                    const float z = __bfloat162float(Ein[o]) * sigmoid_f(v);
                    ((__hip_bfloat16*)C0)[o] = __float2bfloat16(z * sigmoid_f(z));
                } else {  // EPI 5
                    if (col < DE_)
                        ((__hip_bfloat16*)C0)[(size_t)row * DE_ + col] = __float2bfloat16(v);
                    else
                        ((__hip_bfloat16*)C1)[(size_t)row * DG_ + (col - DE_)] =
                            __float2bfloat16(v * sigmoid_f(v));
                }
            }
        }
    }
}

// ---------------------------------------------------------------------------
// MFMA flash attention. Grid (16, B*H); block does q-tiles j and 31-j.
// ---------------------------------------------------------------------------
__global__ __launch_bounds__(256)
void attn_mfma(const __hip_bfloat16* __restrict__ QKV, const __hip_bfloat16* __restrict__ Vt,
               __hip_bfloat16* __restrict__ Y) {
    __shared__ __hip_bfloat16 Ks[128][40];
    __shared__ __hip_bfloat16 Vts[96][136];
    __shared__ __hip_bfloat16 Ps[4][16][72];
    const int tid = threadIdx.x;
    const int lane = tid & 63;
    const int w = tid >> 6;
    const int c = lane & 15;
    const int quad = lane >> 4;
    const int bh = blockIdx.y;
    const int b = bh >> 4, h = bh & 15;
    const size_t qbase = (size_t)b * T_ * QS_ + h * 32;
    const size_t kbase = qbase + 512;
    const size_t vtbase = (size_t)bh * 96 * T_;
    const size_t ybase = (size_t)b * T_ * DM_ + h * 96;
    const float scale2 = 0.17677669529663687f * 1.4426950408889634f;

    for (int half = 0; half < 2; ++half) {
        const int qt = half ? (31 - (int)blockIdx.x) : (int)blockIdx.x;
        const int q0 = qt * 64;
        const int ntiles = (qt >> 1) + 1;
        const int qrow_a = q0 + w * 16 + c;
        const bf16x8_t qf = *(const bf16x8_t*)(QKV + qbase + (size_t)qrow_a * QS_ + quad * 8);

        f32x4_t o[6] = {};
        float mrow[4], lrow[4];
#pragma unroll
        for (int r = 0; r < 4; ++r) { mrow[r] = -1e30f; lrow[r] = 0.f; }
        const int row_c = q0 + w * 16 + quad * 4;

        for (int t = 0; t < ntiles; ++t) {
            const int k0 = t * 128;
#pragma unroll
            for (int p = 0; p < 2; ++p) {
                const int idx = p * 256 + tid;
                const int kr = idx >> 2, cc = idx & 3;
                *(uint4*)(&Ks[kr][cc * 8]) =
                    *(const uint4*)(QKV + kbase + (size_t)(k0 + kr) * QS_ + cc * 8);
            }
#pragma unroll
            for (int p = 0; p < 6; ++p) {
                const int idx = p * 256 + tid;
                const int vr = idx >> 4, vc = idx & 15;
                *(uint4*)(&Vts[vr][vc * 8]) =
                    *(const uint4*)(Vt + vtbase + (size_t)vr * T_ + k0 + vc * 8);
            }
            __syncthreads();

            f32x4_t s[8];
#pragma unroll
            for (int t2 = 0; t2 < 8; ++t2) {
                const bf16x8_t kf = *(const bf16x8_t*)(&Ks[t2 * 16 + c][quad * 8]);
                f32x4_t z = {0.f, 0.f, 0.f, 0.f};
                s[t2] = __builtin_amdgcn_mfma_f32_16x16x32_bf16(qf, kf, z, 0, 0, 0);
            }

            float p[8][4];
            const bool needmask = (k0 + 128 > q0);
            if (needmask) {
#pragma unroll
                for (int t2 = 0; t2 < 8; ++t2) {
                    const int col = k0 + t2 * 16 + c;
#pragma unroll
                    for (int r = 0; r < 4; ++r) {
                        float v = s[t2][r] * scale2;
                        if (col > row_c + r) v = -1e30f;
                        p[t2][r] = v;
                    }
                }
            } else {
#pragma unroll
                for (int t2 = 0; t2 < 8; ++t2)
#pragma unroll
                    for (int r = 0; r < 4; ++r) p[t2][r] = s[t2][r] * scale2;
            }

#pragma unroll
            for (int r = 0; r < 4; ++r) {
                float mx = p[0][r];
#pragma unroll
                for (int t2 = 1; t2 < 8; ++t2) mx = fmaxf(mx, p[t2][r]);
#pragma unroll
                for (int o2 = 1; o2 < 16; o2 <<= 1) mx = fmaxf(mx, __shfl_xor(mx, o2));
                const float mnew = fmaxf(mrow[r], mx);
                const float alpha = exp2f(mrow[r] - mnew);
                mrow[r] = mnew;
                float rsum = 0.f;
#pragma unroll
                for (int t2 = 0; t2 < 8; ++t2) {
                    p[t2][r] = exp2f(p[t2][r] - mnew);
                    rsum += p[t2][r];
                }
#pragma unroll
                for (int o2 = 1; o2 < 16; o2 <<= 1) rsum += __shfl_xor(rsum, o2);
                lrow[r] = lrow[r] * alpha + rsum;
#pragma unroll
                for (int nb = 0; nb < 6; ++nb) o[nb][r] *= alpha;
            }

#pragma unroll
            for (int hh = 0; hh < 2; ++hh) {
#pragma unroll
                for (int t2 = 0; t2 < 4; ++t2)
#pragma unroll
                    for (int r = 0; r < 4; ++r)
                        Ps[w][quad * 4 + r][t2 * 16 + c] = __float2bfloat16(p[hh * 4 + t2][r]);
                const bf16x8_t pf0 = *(const bf16x8_t*)(&Ps[w][c][quad * 8]);
                const bf16x8_t pf1 = *(const bf16x8_t*)(&Ps[w][c][32 + quad * 8]);
#pragma unroll
                for (int nb = 0; nb < 6; ++nb) {
                    const bf16x8_t vf0 = *(const bf16x8_t*)(&Vts[nb * 16 + c][hh * 64 + quad * 8]);
                    o[nb] = __builtin_amdgcn_mfma_f32_16x16x32_bf16(pf0, vf0, o[nb], 0, 0, 0);
                    const bf16x8_t vf1 = *(const bf16x8_t*)(&Vts[nb * 16 + c][hh * 64 + 32 + quad * 8]);
                    o[nb] = __builtin_amdgcn_mfma_f32_16x16x32_bf16(pf1, vf1, o[nb], 0, 0, 0);
                }
            }
            __syncthreads();
        }

#pragma unroll
        for (int r = 0; r < 4; ++r) {
            const float inv = 1.f / lrow[r];
            const size_t rowoff = ybase + (size_t)(row_c + r) * DM_;
#pragma unroll
            for (int nb = 0; nb < 6; ++nb)
                Y[rowoff + nb * 16 + c] = __float2bfloat16(o[nb][r] * inv);
        }
    }
}

// ---------------------------------------------------------------------------
// Workspace map (99 MB; phase-aliased, lifetimes stream-ordered):
//   [  0,  5) wqkvT   [ 5, 8) woT   [ 8,18) wewgT (weT 8..16 | wgT 16..18)
//   [ 18,26) wuT   [26,34) wcT   [34, +16K) bqkv   [+16K, +64K) bewg
//   [ 35,43) x1b -> x2b
//   [ 43,63) qkv -> xmid fp32 (43..59)
//   [ 63,75) vt    [75,87) yb
//   [ 59,91) eb (vt/yb dead by then; EPI4 in-place)   [91,99) hb
// ---------------------------------------------------------------------------
extern "C" void kernel_launch(void* const* d_in, const int* in_sizes, int n_in,
                              void* d_out, int out_size, void* d_ws, size_t ws_size,
                              hipStream_t stream) {
    const float* x     = (const float*)d_in[0];
    const float* ln1_w = (const float*)d_in[2];
    const float* ln1_b = (const float*)d_in[3];
    const float* wq = (const float*)d_in[4];  const float* bq = (const float*)d_in[5];
    const float* wk = (const float*)d_in[6];  const float* bk = (const float*)d_in[7];
    const float* wv = (const float*)d_in[8];  const float* bv = (const float*)d_in[9];
    const float* wo = (const float*)d_in[10]; const float* bo = (const float*)d_in[11];
    const float* ln2_w = (const float*)d_in[12];
    const float* ln2_b = (const float*)d_in[13];
    const float* we = (const float*)d_in[14]; const float* be = (const float*)d_in[15];
    const float* wg = (const float*)d_in[16]; const float* bg = (const float*)d_in[17];
    const float* wu = (const float*)d_in[18]; const float* bu = (const float*)d_in[19];
    const float* wc = (const float*)d_in[20]; const float* bc = (const float*)d_in[21];
    float* out = (float*)d_out;

    char* ws = (char*)d_ws;
    typedef __hip_bfloat16 bf16;
    bf16* wqkvT = (bf16*)(ws + (size_t) 0 * MB);
    bf16* wqT   = wqkvT;
    bf16* wkT   = (bf16*)(ws + (size_t) 1 * MB);
    bf16* wvT   = (bf16*)(ws + (size_t) 2 * MB);
    bf16* woT   = (bf16*)(ws + (size_t) 5 * MB);
    bf16* wewgT = (bf16*)(ws + (size_t) 8 * MB);
    bf16* weT   = wewgT;
    bf16* wgT   = (bf16*)(ws + (size_t)16 * MB);
    bf16* wuT   = (bf16*)(ws + (size_t)18 * MB);
    bf16* wcT   = (bf16*)(ws + (size_t)26 * MB);
    float* bqkv = (float*)(ws + (size_t)34 * MB);
    float* bewg = (float*)(ws + (size_t)34 * MB + 65536);
    bf16* x1b   = (bf16*)(ws + (size_t)35 * MB);
    bf16* x2b   = x1b;
    bf16* qkv   = (bf16*)(ws + (size_t)43 * MB);
    float* xmid = (float*)(ws + (size_t)43 * MB);
    bf16* vt    = (bf16*)(ws + (size_t)63 * MB);
    bf16* yb    = (bf16*)(ws + (size_t)75 * MB);
    bf16* eb    = (bf16*)(ws + (size_t)59 * MB);
    bf16* hb    = (bf16*)(ws + (size_t)91 * MB);

    const dim3 tb(32, 8);
    transpose_cast<<<dim3(DC_ / 32, D_ / 32), tb, 0, stream>>>(wq, wqT, D_, DC_);
    transpose_cast<<<dim3(DC_ / 32, D_ / 32), tb, 0, stream>>>(wk, wkT, D_, DC_);
    transpose_cast<<<dim3(DM_ / 32, D_ / 32), tb, 0, stream>>>(wv, wvT, D_, DM_);
    transpose_cast<<<dim3(D_ / 32, DM_ / 32), tb, 0, stream>>>(wo, woT, DM_, D_);
    transpose_cast<<<dim3(DE_ / 32, D_ / 32), tb, 0, stream>>>(we, weT, D_, DE_);
    transpose_cast<<<dim3(DG_ / 32, D_ / 32), tb, 0, stream>>>(wg, wgT, D_, DG_);
    transpose_cast<<<dim3(DE_ / 32, DG_ / 32), tb, 0, stream>>>(wu, wuT, DG_, DE_);
    transpose_cast<<<dim3(D_ / 32, DE_ / 32), tb, 0, stream>>>(wc, wcT, DE_, D_);
    concat_bias3<<<(QS_ + 255) / 256, 256, 0, stream>>>(bq, 512, bk, 512, bv, QS_, bqkv);
    concat_bias3<<<(EG_ + 255) / 256, 256, 0, stream>>>(be, DE_, bg, DG_, nullptr, EG_, bewg);

    ln_cast<<<ROWS, 256, 0, stream>>>(x, ln1_w, ln1_b, x1b);

    gemm_bt<0, 128, 128><<<dim3(QS_ / 128, ROWS / 128), 256, 0, stream>>>(
        x1b, wqkvT, bqkv, nullptr, nullptr, qkv, nullptr, ROWS, QS_, D_);

    transpose_v<<<dim3(T_ / 32, 3, B_ * H_), tb, 0, stream>>>(qkv, vt);

    attn_mfma<<<dim3(16, B_ * H_), 256, 0, stream>>>(qkv, vt, yb);

    gemm_bt<1, 64, 64><<<dim3(D_ / 64, ROWS / 64), 256, 0, stream>>>(
        yb, woT, bo, x, nullptr, xmid, nullptr, ROWS, D_, DM_);

    ln_cast<<<ROWS, 256, 0, stream>>>(xmid, ln2_w, ln2_b, x2b);

    gemm_bt<5, 128, 128><<<dim3(EG_ / 128, ROWS / 128), 256, 0, stream>>>(
        x2b, wewgT, bewg, nullptr, nullptr, eb, hb, ROWS, EG_, D_);

    gemm_bt<4, 128, 128><<<dim3(DE_ / 128, ROWS / 128), 256, 0, stream>>>(
        hb, wuT, bu, nullptr, eb, eb, nullptr, ROWS, DE_, DG_);

    gemm_bt<1, 64, 64><<<dim3(D_ / 64, ROWS / 64), 256, 0, stream>>>(
        eb, wcT, bc, xmid, nullptr, out, nullptr, ROWS, D_, DE_);
}

// Round 6
// 517.646 us; speedup vs baseline: 1.4100x; 1.0943x over previous
//
#include <hip/hip_runtime.h>
#include <hip/hip_bf16.h>

typedef __bf16 bf16x8_t __attribute__((ext_vector_type(8)));
typedef float f32x4_t __attribute__((ext_vector_type(4)));

#define B_ 2
#define T_ 2048
#define D_ 1024
#define DC_ 512
#define DM_ 1536
#define H_ 16
#define DE_ 4096
#define DG_ 1024
#define ROWS (B_*T_)   // 4096
#define QS_ 2560       // fused q|k|v row stride
#define EG_ 5120       // fused we|wg N
#define MB (1u<<20)

#define GPTR(p) ((const __attribute__((address_space(1))) unsigned int*)(p))
#define LPTR(p) ((__attribute__((address_space(3))) unsigned int*)(p))

__device__ __forceinline__ float sigmoid_f(float x) { return 1.f / (1.f + __expf(-x)); }

// ---------------------------------------------------------------------------
// Weight transpose + cast: W[K,N] fp32 -> Wt[N,K] bf16
// ---------------------------------------------------------------------------
__global__ __launch_bounds__(256)
void transpose_cast(const float* __restrict__ W, __hip_bfloat16* __restrict__ Wt,
                    int K, int N) {
    __shared__ float t[32][33];
    const int n0 = blockIdx.x * 32, k0 = blockIdx.y * 32;
    const int tx = threadIdx.x, ty = threadIdx.y;
#pragma unroll
    for (int r = 0; r < 4; ++r)
        t[ty + r * 8][tx] = W[(size_t)(k0 + ty + r * 8) * N + n0 + tx];
    __syncthreads();
#pragma unroll
    for (int r = 0; r < 4; ++r)
        Wt[(size_t)(n0 + ty + r * 8) * K + k0 + tx] = __float2bfloat16(t[tx][ty + r * 8]);
}

// ---------------------------------------------------------------------------
__global__ __launch_bounds__(256)
void concat_bias3(const float* __restrict__ a, int na, const float* __restrict__ b,
                  int nb, const float* __restrict__ c, int n, float* __restrict__ o) {
    const int i = blockIdx.x * 256 + threadIdx.x;
    if (i < n)
        o[i] = i < na ? a[i] : (i < na + nb ? b[i - na] : c[i - na - nb]);
}

// ---------------------------------------------------------------------------
// V transpose out of fused qkv: QKV[b*T+t][1024 + h*96 + d] -> Vt[(bh*96+d)][t]
// ---------------------------------------------------------------------------
__global__ __launch_bounds__(256)
void transpose_v(const __hip_bfloat16* __restrict__ QKV, __hip_bfloat16* __restrict__ Vt) {
    __shared__ __hip_bfloat16 t[32][33];
    const int bh = blockIdx.z;
    const int b = bh >> 4, h = bh & 15;
    const int t0 = blockIdx.x * 32;
    const int d0 = blockIdx.y * 32;
    const int tx = threadIdx.x, ty = threadIdx.y;  // (32,8)
#pragma unroll
    for (int r = 0; r < 4; ++r)
        t[ty + r * 8][tx] = QKV[(size_t)(b * T_ + t0 + ty + r * 8) * QS_ + 1024 + h * 96 + d0 + tx];
    __syncthreads();
#pragma unroll
    for (int r = 0; r < 4; ++r)
        Vt[((size_t)bh * 96 + d0 + ty + r * 8) * T_ + t0 + tx] = t[tx][ty + r * 8];
}

// ---------------------------------------------------------------------------
// LayerNorm over D=1024, fp32 in -> bf16 out. One block (256 thr) per row.
// ---------------------------------------------------------------------------
__global__ __launch_bounds__(256)
void ln_cast(const float* __restrict__ x, const float* __restrict__ w,
             const float* __restrict__ b, __hip_bfloat16* __restrict__ out) {
    const int row = blockIdx.x;
    const int tid = threadIdx.x;
    const float4 v = ((const float4*)(x + (size_t)row * D_))[tid];
    float s = v.x + v.y + v.z + v.w;
#pragma unroll
    for (int o = 32; o; o >>= 1) s += __shfl_down(s, o);
    __shared__ float red1[4], red2[4];
    if (!(tid & 63)) red1[tid >> 6] = s;
    __syncthreads();
    const float mu = (red1[0] + red1[1] + red1[2] + red1[3]) * (1.f / D_);
    const float dx = v.x - mu, dy = v.y - mu, dz = v.z - mu, dw = v.w - mu;
    float s2 = dx * dx + dy * dy + dz * dz + dw * dw;
#pragma unroll
    for (int o = 32; o; o >>= 1) s2 += __shfl_down(s2, o);
    if (!(tid & 63)) red2[tid >> 6] = s2;
    __syncthreads();
    const float var = (red2[0] + red2[1] + red2[2] + red2[3]) * (1.f / D_);
    const float rs = rsqrtf(var + 1e-5f);
    const float4 wv = ((const float4*)w)[tid];
    const float4 bv = ((const float4*)b)[tid];
    __hip_bfloat16* op = out + (size_t)row * D_ + tid * 4;
    op[0] = __float2bfloat16(dx * rs * wv.x + bv.x);
    op[1] = __float2bfloat16(dy * rs * wv.y + bv.y);
    op[2] = __float2bfloat16(dz * rs * wv.z + bv.z);
    op[3] = __float2bfloat16(dw * rs * wv.w + bv.w);
}

// ---------------------------------------------------------------------------
// bf16 MFMA GEMM: double-buffered global_load_lds K-loop (1 barrier/iter,
// prefetch overlaps compute) + LDS-staged vectorized epilogue (full-sector
// 16B stores; Ein/resid reads coalesced).
// LDS slot swizzle: slot s holds chunk (s&3)^((row>>1)&3) of row s>>2.
// EPI 0: bf16;  1: fp32 = resid + v;  4: bf16 = silu(Ein*sigmoid(v)) in-place;
// EPI 5: col<DE -> C0 bf16 (stride DE), col>=DE -> C1 bf16 silu(v) (stride DG)
// ---------------------------------------------------------------------------
template <int EPI, int BM, int BN>
__global__ __launch_bounds__(256)
void gemm_bt(const __hip_bfloat16* __restrict__ A, const __hip_bfloat16* __restrict__ Bt,
             const float* __restrict__ bias, const float* __restrict__ resid,
             const __hip_bfloat16* __restrict__ Ein,
             void* __restrict__ C0, void* __restrict__ C1, int M, int N, int K) {
    constexpr int MI = BM / 32, NJ = BN / 32;
    constexpr size_t STAGE_BYTES = (size_t)(BM + BN) * 128;   // 2 bufs
    constexpr size_t EPI_BYTES = (EPI == 1) ? (size_t)BM * (BN + 4) * 4
                                            : (size_t)BM * (BN + 8) * 2;
    constexpr size_t SMEM_BYTES = STAGE_BYTES > EPI_BYTES ? STAGE_BYTES : EPI_BYTES;
    __shared__ __align__(16) unsigned char smem[SMEM_BYTES];
    __hip_bfloat16* As0 = (__hip_bfloat16*)smem;
    __hip_bfloat16* Bs0 = As0 + BM * 32;
    __hip_bfloat16* As1 = Bs0 + BN * 32;
    __hip_bfloat16* Bs1 = As1 + BM * 32;

    const int tid = threadIdx.x;
    const int m0 = blockIdx.y * BM;
    const int n0 = blockIdx.x * BN;
    const int lane = tid & 63;
    const int wave = tid >> 6;
    const int wm = (wave >> 1) * (BM / 2), wn = (wave & 1) * (BN / 2);
    const int quad = lane >> 4;
    const int lr = lane & 15;

    auto stage = [&](int k0, __hip_bfloat16* Asd, __hip_bfloat16* Bsd) {
#pragma unroll
        for (int p = 0; p < BM / 64; ++p) {
            const int s = p * 256 + tid;
            const int row = s >> 2;
            const int kc2 = (s & 3) ^ ((row >> 1) & 3);
            __builtin_amdgcn_global_load_lds(
                GPTR(A + (size_t)(m0 + row) * K + k0 + kc2 * 8),
                LPTR(Asd + s * 8), 16, 0, 0);
        }
#pragma unroll
        for (int p = 0; p < BN / 64; ++p) {
            const int s = p * 256 + tid;
            const int row = s >> 2;
            const int kc2 = (s & 3) ^ ((row >> 1) & 3);
            __builtin_amdgcn_global_load_lds(
                GPTR(Bt + (size_t)(n0 + row) * K + k0 + kc2 * 8),
                LPTR(Bsd + s * 8), 16, 0, 0);
        }
    };

    f32x4_t acc[MI][NJ] = {};
    stage(0, As0, Bs0);
    const int kiters = K >> 5;
    for (int k = 0; k < kiters; ++k) {
        __syncthreads();   // drains this buffer's loads; prev compute done
        const __hip_bfloat16* Ar = (k & 1) ? As1 : As0;
        const __hip_bfloat16* Br = (k & 1) ? Bs1 : Bs0;
        if (k + 1 < kiters)
            stage((k + 1) << 5, (k & 1) ? As0 : As1, (k & 1) ? Bs0 : Bs1);
        bf16x8_t af[MI], bfr[NJ];
#pragma unroll
        for (int i = 0; i < MI; ++i) {
            const int row = wm + i * 16 + lr;
            af[i] = *(const bf16x8_t*)(Ar + (row * 4 + (quad ^ ((row >> 1) & 3))) * 8);
        }
#pragma unroll
        for (int j = 0; j < NJ; ++j) {
            const int row = wn + j * 16 + lr;
            bfr[j] = *(const bf16x8_t*)(Br + (row * 4 + (quad ^ ((row >> 1) & 3))) * 8);
        }
#pragma unroll
        for (int i = 0; i < MI; ++i)
#pragma unroll
            for (int j = 0; j < NJ; ++j)
                acc[i][j] = __builtin_amdgcn_mfma_f32_16x16x32_bf16(af[i], bfr[j], acc[i][j], 0, 0, 0);
    }
    __syncthreads();   // all waves done reading smem before epilogue reuse

    if (EPI == 1) {
        float* Ct = (float*)smem;
        constexpr int LDC = BN + 4;
#pragma unroll
        for (int j = 0; j < NJ; ++j) {
            const float bj = bias[n0 + wn + j * 16 + lr];
#pragma unroll
            for (int i = 0; i < MI; ++i)
#pragma unroll
                for (int r = 0; r < 4; ++r)
                    Ct[(wm + i * 16 + quad * 4 + r) * LDC + wn + j * 16 + lr] =
                        acc[i][j][r] + bj;
        }
        __syncthreads();
        constexpr int CH = BN / 4;
#pragma unroll
        for (int p = 0; p < BM * CH / 256; ++p) {
            const int s = p * 256 + tid;
            const int row = s / CH, ch = s % CH;
            float4 t = *(const float4*)(&Ct[row * LDC + ch * 4]);
            const size_t o = (size_t)(m0 + row) * N + n0 + ch * 4;
            const float4 rv = *(const float4*)(resid + o);
            t.x += rv.x; t.y += rv.y; t.z += rv.z; t.w += rv.w;
            *(float4*)((float*)C0 + o) = t;
        }
    } else {
        __hip_bfloat16* Ct = (__hip_bfloat16*)smem;
        constexpr int LDC = BN + 8;
        const bool gsilu = (EPI == 5) && (n0 >= DE_);   // block-uniform
#pragma unroll
        for (int j = 0; j < NJ; ++j) {
            const float bj = bias[n0 + wn + j * 16 + lr];
#pragma unroll
            for (int i = 0; i < MI; ++i)
#pragma unroll
                for (int r = 0; r < 4; ++r) {
                    float v = acc[i][j][r] + bj;
                    if (EPI == 4) v = sigmoid_f(v);
                    else if (EPI == 5) { if (gsilu) v = v * sigmoid_f(v); }
                    Ct[(wm + i * 16 + quad * 4 + r) * LDC + wn + j * 16 + lr] =
                        __float2bfloat16(v);
                }
        }
        __syncthreads();
        constexpr int CH = BN / 8;
#pragma unroll
        for (int p = 0; p < BM * CH / 256; ++p) {
            const int s = p * 256 + tid;
            const int row = s / CH, ch = s % CH;
            union { uint4 u; __hip_bfloat16 h[8]; } tv, ev, ov;
            tv.u = *(const uint4*)(&Ct[row * LDC + ch * 8]);
            if (EPI == 4) {
                const size_t o = (size_t)(m0 + row) * N + n0 + ch * 8;
                ev.u = *(const uint4*)(Ein + o);
#pragma unroll
                for (int q = 0; q < 8; ++q) {
                    const float z = __bfloat162float(ev.h[q]) * __bfloat162float(tv.h[q]);
                    ov.h[q] = __float2bfloat16(z * sigmoid_f(z));
                }
                *(uint4*)((__hip_bfloat16*)C0 + o) = ov.u;
            } else if (EPI == 5) {
                if (n0 < DE_)
                    *(uint4*)((__hip_bfloat16*)C0 + (size_t)(m0 + row) * DE_ + n0 + ch * 8) = tv.u;
                else
                    *(uint4*)((__hip_bfloat16*)C1 + (size_t)(m0 + row) * DG_ + (n0 - DE_) + ch * 8) = tv.u;
            } else {
                *(uint4*)((__hip_bfloat16*)C0 + (size_t)(m0 + row) * N + n0 + ch * 8) = tv.u;
            }
        }
    }
}

// ---------------------------------------------------------------------------
// MFMA flash attention. Grid (16, B*H); block does q-tiles j and 31-j.
// ---------------------------------------------------------------------------
__global__ __launch_bounds__(256)
void attn_mfma(const __hip_bfloat16* __restrict__ QKV, const __hip_bfloat16* __restrict__ Vt,
               __hip_bfloat16* __restrict__ Y) {
    __shared__ __hip_bfloat16 Ks[128][40];
    __shared__ __hip_bfloat16 Vts[96][136];
    __shared__ __hip_bfloat16 Ps[4][16][72];
    const int tid = threadIdx.x;
    const int lane = tid & 63;
    const int w = tid >> 6;
    const int c = lane & 15;
    const int quad = lane >> 4;
    const int bh = blockIdx.y;
    const int b = bh >> 4, h = bh & 15;
    const size_t qbase = (size_t)b * T_ * QS_ + h * 32;
    const size_t kbase = qbase + 512;
    const size_t vtbase = (size_t)bh * 96 * T_;
    const size_t ybase = (size_t)b * T_ * DM_ + h * 96;
    const float scale2 = 0.17677669529663687f * 1.4426950408889634f;

    for (int half = 0; half < 2; ++half) {
        const int qt = half ? (31 - (int)blockIdx.x) : (int)blockIdx.x;
        const int q0 = qt * 64;
        const int ntiles = (qt >> 1) + 1;
        const int qrow_a = q0 + w * 16 + c;
        const bf16x8_t qf = *(const bf16x8_t*)(QKV + qbase + (size_t)qrow_a * QS_ + quad * 8);

        f32x4_t o[6] = {};
        float mrow[4], lrow[4];
#pragma unroll
        for (int r = 0; r < 4; ++r) { mrow[r] = -1e30f; lrow[r] = 0.f; }
        const int row_c = q0 + w * 16 + quad * 4;

        for (int t = 0; t < ntiles; ++t) {
            const int k0 = t * 128;
#pragma unroll
            for (int p = 0; p < 2; ++p) {
                const int idx = p * 256 + tid;
                const int kr = idx >> 2, cc = idx & 3;
                *(uint4*)(&Ks[kr][cc * 8]) =
                    *(const uint4*)(QKV + kbase + (size_t)(k0 + kr) * QS_ + cc * 8);
            }
#pragma unroll
            for (int p = 0; p < 6; ++p) {
                const int idx = p * 256 + tid;
                const int vr = idx >> 4, vc = idx & 15;
                *(uint4*)(&Vts[vr][vc * 8]) =
                    *(const uint4*)(Vt + vtbase + (size_t)vr * T_ + k0 + vc * 8);
            }
            __syncthreads();

            f32x4_t s[8];
#pragma unroll
            for (int t2 = 0; t2 < 8; ++t2) {
                const bf16x8_t kf = *(const bf16x8_t*)(&Ks[t2 * 16 + c][quad * 8]);
                f32x4_t z = {0.f, 0.f, 0.f, 0.f};
                s[t2] = __builtin_amdgcn_mfma_f32_16x16x32_bf16(qf, kf, z, 0, 0, 0);
            }

            float p[8][4];
            const bool needmask = (k0 + 128 > q0);
            if (needmask) {
#pragma unroll
                for (int t2 = 0; t2 < 8; ++t2) {
                    const int col = k0 + t2 * 16 + c;
#pragma unroll
                    for (int r = 0; r < 4; ++r) {
                        float v = s[t2][r] * scale2;
                        if (col > row_c + r) v = -1e30f;
                        p[t2][r] = v;
                    }
                }
            } else {
#pragma unroll
                for (int t2 = 0; t2 < 8; ++t2)
#pragma unroll
                    for (int r = 0; r < 4; ++r) p[t2][r] = s[t2][r] * scale2;
            }

#pragma unroll
            for (int r = 0; r < 4; ++r) {
                float mx = p[0][r];
#pragma unroll
                for (int t2 = 1; t2 < 8; ++t2) mx = fmaxf(mx, p[t2][r]);
#pragma unroll
                for (int o2 = 1; o2 < 16; o2 <<= 1) mx = fmaxf(mx, __shfl_xor(mx, o2));
                const float mnew = fmaxf(mrow[r], mx);
                const float alpha = exp2f(mrow[r] - mnew);
                mrow[r] = mnew;
                float rsum = 0.f;
#pragma unroll
                for (int t2 = 0; t2 < 8; ++t2) {
                    p[t2][r] = exp2f(p[t2][r] - mnew);
                    rsum += p[t2][r];
                }
#pragma unroll
                for (int o2 = 1; o2 < 16; o2 <<= 1) rsum += __shfl_xor(rsum, o2);
                lrow[r] = lrow[r] * alpha + rsum;
#pragma unroll
                for (int nb = 0; nb < 6; ++nb) o[nb][r] *= alpha;
            }

#pragma unroll
            for (int hh = 0; hh < 2; ++hh) {
#pragma unroll
                for (int t2 = 0; t2 < 4; ++t2)
#pragma unroll
                    for (int r = 0; r < 4; ++r)
                        Ps[w][quad * 4 + r][t2 * 16 + c] = __float2bfloat16(p[hh * 4 + t2][r]);
                const bf16x8_t pf0 = *(const bf16x8_t*)(&Ps[w][c][quad * 8]);
                const bf16x8_t pf1 = *(const bf16x8_t*)(&Ps[w][c][32 + quad * 8]);
#pragma unroll
                for (int nb = 0; nb < 6; ++nb) {
                    const bf16x8_t vf0 = *(const bf16x8_t*)(&Vts[nb * 16 + c][hh * 64 + quad * 8]);
                    o[nb] = __builtin_amdgcn_mfma_f32_16x16x32_bf16(pf0, vf0, o[nb], 0, 0, 0);
                    const bf16x8_t vf1 = *(const bf16x8_t*)(&Vts[nb * 16 + c][hh * 64 + 32 + quad * 8]);
                    o[nb] = __builtin_amdgcn_mfma_f32_16x16x32_bf16(pf1, vf1, o[nb], 0, 0, 0);
                }
            }
            __syncthreads();
        }

#pragma unroll
        for (int r = 0; r < 4; ++r) {
            const float inv = 1.f / lrow[r];
            const size_t rowoff = ybase + (size_t)(row_c + r) * DM_;
#pragma unroll
            for (int nb = 0; nb < 6; ++nb)
                Y[rowoff + nb * 16 + c] = __float2bfloat16(o[nb][r] * inv);
        }
    }
}

// ---------------------------------------------------------------------------
// Workspace map (99 MB; phase-aliased, lifetimes stream-ordered):
//   [  0,  5) wqkvT   [ 5, 8) woT   [ 8,18) wewgT (weT 8..16 | wgT 16..18)
//   [ 18,26) wuT   [26,34) wcT   [34, +16K) bqkv   [+16K, +64K) bewg
//   [ 35,43) x1b -> x2b
//   [ 43,63) qkv -> xmid fp32 (43..59)
//   [ 63,75) vt    [75,87) yb
//   [ 59,91) eb (vt/yb dead by then; EPI4 in-place)   [91,99) hb
// ---------------------------------------------------------------------------
extern "C" void kernel_launch(void* const* d_in, const int* in_sizes, int n_in,
                              void* d_out, int out_size, void* d_ws, size_t ws_size,
                              hipStream_t stream) {
    const float* x     = (const float*)d_in[0];
    const float* ln1_w = (const float*)d_in[2];
    const float* ln1_b = (const float*)d_in[3];
    const float* wq = (const float*)d_in[4];  const float* bq = (const float*)d_in[5];
    const float* wk = (const float*)d_in[6];  const float* bk = (const float*)d_in[7];
    const float* wv = (const float*)d_in[8];  const float* bv = (const float*)d_in[9];
    const float* wo = (const float*)d_in[10]; const float* bo = (const float*)d_in[11];
    const float* ln2_w = (const float*)d_in[12];
    const float* ln2_b = (const float*)d_in[13];
    const float* we = (const float*)d_in[14]; const float* be = (const float*)d_in[15];
    const float* wg = (const float*)d_in[16]; const float* bg = (const float*)d_in[17];
    const float* wu = (const float*)d_in[18]; const float* bu = (const float*)d_in[19];
    const float* wc = (const float*)d_in[20]; const float* bc = (const float*)d_in[21];
    float* out = (float*)d_out;

    char* ws = (char*)d_ws;
    typedef __hip_bfloat16 bf16;
    bf16* wqkvT = (bf16*)(ws + (size_t) 0 * MB);
    bf16* wqT   = wqkvT;
    bf16* wkT   = (bf16*)(ws + (size_t) 1 * MB);
    bf16* wvT   = (bf16*)(ws + (size_t) 2 * MB);
    bf16* woT   = (bf16*)(ws + (size_t) 5 * MB);
    bf16* wewgT = (bf16*)(ws + (size_t) 8 * MB);
    bf16* weT   = wewgT;
    bf16* wgT   = (bf16*)(ws + (size_t)16 * MB);
    bf16* wuT   = (bf16*)(ws + (size_t)18 * MB);
    bf16* wcT   = (bf16*)(ws + (size_t)26 * MB);
    float* bqkv = (float*)(ws + (size_t)34 * MB);
    float* bewg = (float*)(ws + (size_t)34 * MB + 65536);
    bf16* x1b   = (bf16*)(ws + (size_t)35 * MB);
    bf16* x2b   = x1b;
    bf16* qkv   = (bf16*)(ws + (size_t)43 * MB);
    float* xmid = (float*)(ws + (size_t)43 * MB);
    bf16* vt    = (bf16*)(ws + (size_t)63 * MB);
    bf16* yb    = (bf16*)(ws + (size_t)75 * MB);
    bf16* eb    = (bf16*)(ws + (size_t)59 * MB);
    bf16* hb    = (bf16*)(ws + (size_t)91 * MB);

    const dim3 tb(32, 8);
    transpose_cast<<<dim3(DC_ / 32, D_ / 32), tb, 0, stream>>>(wq, wqT, D_, DC_);
    transpose_cast<<<dim3(DC_ / 32, D_ / 32), tb, 0, stream>>>(wk, wkT, D_, DC_);
    transpose_cast<<<dim3(DM_ / 32, D_ / 32), tb, 0, stream>>>(wv, wvT, D_, DM_);
    transpose_cast<<<dim3(D_ / 32, DM_ / 32), tb, 0, stream>>>(wo, woT, DM_, D_);
    transpose_cast<<<dim3(DE_ / 32, D_ / 32), tb, 0, stream>>>(we, weT, D_, DE_);
    transpose_cast<<<dim3(DG_ / 32, D_ / 32), tb, 0, stream>>>(wg, wgT, D_, DG_);
    transpose_cast<<<dim3(DE_ / 32, DG_ / 32), tb, 0, stream>>>(wu, wuT, DG_, DE_);
    transpose_cast<<<dim3(D_ / 32, DE_ / 32), tb, 0, stream>>>(wc, wcT, DE_, D_);
    concat_bias3<<<(QS_ + 255) / 256, 256, 0, stream>>>(bq, 512, bk, 512, bv, QS_, bqkv);
    concat_bias3<<<(EG_ + 255) / 256, 256, 0, stream>>>(be, DE_, bg, DG_, nullptr, EG_, bewg);

    ln_cast<<<ROWS, 256, 0, stream>>>(x, ln1_w, ln1_b, x1b);

    gemm_bt<0, 128, 128><<<dim3(QS_ / 128, ROWS / 128), 256, 0, stream>>>(
        x1b, wqkvT, bqkv, nullptr, nullptr, qkv, nullptr, ROWS, QS_, D_);

    transpose_v<<<dim3(T_ / 32, 3, B_ * H_), tb, 0, stream>>>(qkv, vt);

    attn_mfma<<<dim3(16, B_ * H_), 256, 0, stream>>>(qkv, vt, yb);

    gemm_bt<1, 64, 64><<<dim3(D_ / 64, ROWS / 64), 256, 0, stream>>>(
        yb, woT, bo, x, nullptr, xmid, nullptr, ROWS, D_, DM_);

    ln_cast<<<ROWS, 256, 0, stream>>>(xmid, ln2_w, ln2_b, x2b);

    gemm_bt<5, 128, 128><<<dim3(EG_ / 128, ROWS / 128), 256, 0, stream>>>(
        x2b, wewgT, bewg, nullptr, nullptr, eb, hb, ROWS, EG_, D_);

    gemm_bt<4, 128, 128><<<dim3(DE_ / 128, ROWS / 128), 256, 0, stream>>>(
        hb, wuT, bu, nullptr, eb, eb, nullptr, ROWS, DE_, DG_);

    gemm_bt<1, 64, 64><<<dim3(D_ / 64, ROWS / 64), 256, 0, stream>>>(
        eb, wcT, bc, xmid, nullptr, out, nullptr, ROWS, D_, DE_);
}

// Round 7
// 493.035 us; speedup vs baseline: 1.4804x; 1.0499x over previous
//
#include <hip/hip_runtime.h>
#include <hip/hip_bf16.h>

typedef __bf16 bf16x8_t __attribute__((ext_vector_type(8)));
typedef float f32x4_t __attribute__((ext_vector_type(4)));

#define B_ 2
#define T_ 2048
#define D_ 1024
#define DC_ 512
#define DM_ 1536
#define H_ 16
#define DE_ 4096
#define DG_ 1024
#define ROWS (B_*T_)   // 4096
#define QS_ 2560       // fused q|k|v row stride
#define EG_ 5120       // fused we|wg N
#define MB (1u<<20)

#define GPTR(p) ((const __attribute__((address_space(1))) unsigned int*)(p))
#define LPTR(p) ((__attribute__((address_space(3))) unsigned int*)(p))

__device__ __forceinline__ float sigmoid_f(float x) { return 1.f / (1.f + __expf(-x)); }

// ---------------------------------------------------------------------------
// Batched weight transpose+cast: 8 segments of W[K,N] fp32 -> Wt[N,K] bf16
// ---------------------------------------------------------------------------
struct TCTab {
    const float* src[8];
    __hip_bfloat16* dst[8];
    int K[8], N[8];
    int off[8];   // starting 32x32-tile index of each segment
};

__global__ __launch_bounds__(256)
void transpose_cast_all(TCTab tab) {
    __shared__ float t[32][33];
    const int bid = blockIdx.x;
    int sidx = 0;
#pragma unroll
    for (int i = 1; i < 8; ++i) sidx = (bid >= tab.off[i]) ? i : sidx;
    const float* __restrict__ W = tab.src[sidx];
    __hip_bfloat16* __restrict__ Wt = tab.dst[sidx];
    const int K = tab.K[sidx], N = tab.N[sidx];
    const int local = bid - tab.off[sidx];
    const int nx = N >> 5;
    const int n0 = (local % nx) * 32, k0 = (local / nx) * 32;
    const int tx = threadIdx.x, ty = threadIdx.y;
#pragma unroll
    for (int r = 0; r < 4; ++r)
        t[ty + r * 8][tx] = W[(size_t)(k0 + ty + r * 8) * N + n0 + tx];
    __syncthreads();
#pragma unroll
    for (int r = 0; r < 4; ++r)
        Wt[(size_t)(n0 + ty + r * 8) * K + k0 + tx] = __float2bfloat16(t[tx][ty + r * 8]);
}

// ---------------------------------------------------------------------------
__global__ __launch_bounds__(256)
void concat_bias3(const float* __restrict__ a, int na, const float* __restrict__ b,
                  int nb, const float* __restrict__ c, int n, float* __restrict__ o) {
    const int i = blockIdx.x * 256 + threadIdx.x;
    if (i < n)
        o[i] = i < na ? a[i] : (i < na + nb ? b[i - na] : c[i - na - nb]);
}

// ---------------------------------------------------------------------------
// V transpose out of fused qkv: QKV[b*T+t][1024 + h*96 + d] -> Vt[(bh*96+d)][t]
// ---------------------------------------------------------------------------
__global__ __launch_bounds__(256)
void transpose_v(const __hip_bfloat16* __restrict__ QKV, __hip_bfloat16* __restrict__ Vt) {
    __shared__ __hip_bfloat16 t[32][33];
    const int bh = blockIdx.z;
    const int b = bh >> 4, h = bh & 15;
    const int t0 = blockIdx.x * 32;
    const int d0 = blockIdx.y * 32;
    const int tx = threadIdx.x, ty = threadIdx.y;  // (32,8)
#pragma unroll
    for (int r = 0; r < 4; ++r)
        t[ty + r * 8][tx] = QKV[(size_t)(b * T_ + t0 + ty + r * 8) * QS_ + 1024 + h * 96 + d0 + tx];
    __syncthreads();
#pragma unroll
    for (int r = 0; r < 4; ++r)
        Vt[((size_t)bh * 96 + d0 + ty + r * 8) * T_ + t0 + tx] = t[tx][ty + r * 8];
}

// ---------------------------------------------------------------------------
// LayerNorm over D=1024, fp32 in -> bf16 out. One block (256 thr) per row.
// ---------------------------------------------------------------------------
__global__ __launch_bounds__(256)
void ln_cast(const float* __restrict__ x, const float* __restrict__ w,
             const float* __restrict__ b, __hip_bfloat16* __restrict__ out) {
    const int row = blockIdx.x;
    const int tid = threadIdx.x;
    const float4 v = ((const float4*)(x + (size_t)row * D_))[tid];
    float s = v.x + v.y + v.z + v.w;
#pragma unroll
    for (int o = 32; o; o >>= 1) s += __shfl_down(s, o);
    __shared__ float red1[4], red2[4];
    if (!(tid & 63)) red1[tid >> 6] = s;
    __syncthreads();
    const float mu = (red1[0] + red1[1] + red1[2] + red1[3]) * (1.f / D_);
    const float dx = v.x - mu, dy = v.y - mu, dz = v.z - mu, dw = v.w - mu;
    float s2 = dx * dx + dy * dy + dz * dz + dw * dw;
#pragma unroll
    for (int o = 32; o; o >>= 1) s2 += __shfl_down(s2, o);
    if (!(tid & 63)) red2[tid >> 6] = s2;
    __syncthreads();
    const float var = (red2[0] + red2[1] + red2[2] + red2[3]) * (1.f / D_);
    const float rs = rsqrtf(var + 1e-5f);
    const float4 wv = ((const float4*)w)[tid];
    const float4 bv = ((const float4*)b)[tid];
    __hip_bfloat16* op = out + (size_t)row * D_ + tid * 4;
    op[0] = __float2bfloat16(dx * rs * wv.x + bv.x);
    op[1] = __float2bfloat16(dy * rs * wv.y + bv.y);
    op[2] = __float2bfloat16(dz * rs * wv.z + bv.z);
    op[3] = __float2bfloat16(dw * rs * wv.w + bv.w);
}

// ---------------------------------------------------------------------------
// bf16 MFMA GEMM: double-buffered global_load_lds K-loop + LDS-staged
// vectorized epilogue. (unchanged from R6 winner)
// ---------------------------------------------------------------------------
template <int EPI, int BM, int BN>
__global__ __launch_bounds__(256)
void gemm_bt(const __hip_bfloat16* __restrict__ A, const __hip_bfloat16* __restrict__ Bt,
             const float* __restrict__ bias, const float* __restrict__ resid,
             const __hip_bfloat16* __restrict__ Ein,
             void* __restrict__ C0, void* __restrict__ C1, int M, int N, int K) {
    constexpr int MI = BM / 32, NJ = BN / 32;
    constexpr size_t STAGE_BYTES = (size_t)(BM + BN) * 128;   // 2 bufs
    constexpr size_t EPI_BYTES = (EPI == 1) ? (size_t)BM * (BN + 4) * 4
                                            : (size_t)BM * (BN + 8) * 2;
    constexpr size_t SMEM_BYTES = STAGE_BYTES > EPI_BYTES ? STAGE_BYTES : EPI_BYTES;
    __shared__ __align__(16) unsigned char smem[SMEM_BYTES];
    __hip_bfloat16* As0 = (__hip_bfloat16*)smem;
    __hip_bfloat16* Bs0 = As0 + BM * 32;
    __hip_bfloat16* As1 = Bs0 + BN * 32;
    __hip_bfloat16* Bs1 = As1 + BM * 32;

    const int tid = threadIdx.x;
    const int m0 = blockIdx.y * BM;
    const int n0 = blockIdx.x * BN;
    const int lane = tid & 63;
    const int wave = tid >> 6;
    const int wm = (wave >> 1) * (BM / 2), wn = (wave & 1) * (BN / 2);
    const int quad = lane >> 4;
    const int lr = lane & 15;

    auto stage = [&](int k0, __hip_bfloat16* Asd, __hip_bfloat16* Bsd) {
#pragma unroll
        for (int p = 0; p < BM / 64; ++p) {
            const int s = p * 256 + tid;
            const int row = s >> 2;
            const int kc2 = (s & 3) ^ ((row >> 1) & 3);
            __builtin_amdgcn_global_load_lds(
                GPTR(A + (size_t)(m0 + row) * K + k0 + kc2 * 8),
                LPTR(Asd + s * 8), 16, 0, 0);
        }
#pragma unroll
        for (int p = 0; p < BN / 64; ++p) {
            const int s = p * 256 + tid;
            const int row = s >> 2;
            const int kc2 = (s & 3) ^ ((row >> 1) & 3);
            __builtin_amdgcn_global_load_lds(
                GPTR(Bt + (size_t)(n0 + row) * K + k0 + kc2 * 8),
                LPTR(Bsd + s * 8), 16, 0, 0);
        }
    };

    f32x4_t acc[MI][NJ] = {};
    stage(0, As0, Bs0);
    const int kiters = K >> 5;
    for (int k = 0; k < kiters; ++k) {
        __syncthreads();
        const __hip_bfloat16* Ar = (k & 1) ? As1 : As0;
        const __hip_bfloat16* Br = (k & 1) ? Bs1 : Bs0;
        if (k + 1 < kiters)
            stage((k + 1) << 5, (k & 1) ? As0 : As1, (k & 1) ? Bs0 : Bs1);
        bf16x8_t af[MI], bfr[NJ];
#pragma unroll
        for (int i = 0; i < MI; ++i) {
            const int row = wm + i * 16 + lr;
            af[i] = *(const bf16x8_t*)(Ar + (row * 4 + (quad ^ ((row >> 1) & 3))) * 8);
        }
#pragma unroll
        for (int j = 0; j < NJ; ++j) {
            const int row = wn + j * 16 + lr;
            bfr[j] = *(const bf16x8_t*)(Br + (row * 4 + (quad ^ ((row >> 1) & 3))) * 8);
        }
#pragma unroll
        for (int i = 0; i < MI; ++i)
#pragma unroll
            for (int j = 0; j < NJ; ++j)
                acc[i][j] = __builtin_amdgcn_mfma_f32_16x16x32_bf16(af[i], bfr[j], acc[i][j], 0, 0, 0);
    }
    __syncthreads();

    if (EPI == 1) {
        float* Ct = (float*)smem;
        constexpr int LDC = BN + 4;
#pragma unroll
        for (int j = 0; j < NJ; ++j) {
            const float bj = bias[n0 + wn + j * 16 + lr];
#pragma unroll
            for (int i = 0; i < MI; ++i)
#pragma unroll
                for (int r = 0; r < 4; ++r)
                    Ct[(wm + i * 16 + quad * 4 + r) * LDC + wn + j * 16 + lr] =
                        acc[i][j][r] + bj;
        }
        __syncthreads();
        constexpr int CH = BN / 4;
#pragma unroll
        for (int p = 0; p < BM * CH / 256; ++p) {
            const int s = p * 256 + tid;
            const int row = s / CH, ch = s % CH;
            float4 t = *(const float4*)(&Ct[row * LDC + ch * 4]);
            const size_t o = (size_t)(m0 + row) * N + n0 + ch * 4;
            const float4 rv = *(const float4*)(resid + o);
            t.x += rv.x; t.y += rv.y; t.z += rv.z; t.w += rv.w;
            *(float4*)((float*)C0 + o) = t;
        }
    } else {
        __hip_bfloat16* Ct = (__hip_bfloat16*)smem;
        constexpr int LDC = BN + 8;
        const bool gsilu = (EPI == 5) && (n0 >= DE_);
#pragma unroll
        for (int j = 0; j < NJ; ++j) {
            const float bj = bias[n0 + wn + j * 16 + lr];
#pragma unroll
            for (int i = 0; i < MI; ++i)
#pragma unroll
                for (int r = 0; r < 4; ++r) {
                    float v = acc[i][j][r] + bj;
                    if (EPI == 4) v = sigmoid_f(v);
                    else if (EPI == 5) { if (gsilu) v = v * sigmoid_f(v); }
                    Ct[(wm + i * 16 + quad * 4 + r) * LDC + wn + j * 16 + lr] =
                        __float2bfloat16(v);
                }
        }
        __syncthreads();
        constexpr int CH = BN / 8;
#pragma unroll
        for (int p = 0; p < BM * CH / 256; ++p) {
            const int s = p * 256 + tid;
            const int row = s / CH, ch = s % CH;
            union { uint4 u; __hip_bfloat16 h[8]; } tv, ev, ov;
            tv.u = *(const uint4*)(&Ct[row * LDC + ch * 8]);
            if (EPI == 4) {
                const size_t o = (size_t)(m0 + row) * N + n0 + ch * 8;
                ev.u = *(const uint4*)(Ein + o);
#pragma unroll
                for (int q = 0; q < 8; ++q) {
                    const float z = __bfloat162float(ev.h[q]) * __bfloat162float(tv.h[q]);
                    ov.h[q] = __float2bfloat16(z * sigmoid_f(z));
                }
                *(uint4*)((__hip_bfloat16*)C0 + o) = ov.u;
            } else if (EPI == 5) {
                if (n0 < DE_)
                    *(uint4*)((__hip_bfloat16*)C0 + (size_t)(m0 + row) * DE_ + n0 + ch * 8) = tv.u;
                else
                    *(uint4*)((__hip_bfloat16*)C1 + (size_t)(m0 + row) * DG_ + (n0 - DE_) + ch * 8) = tv.u;
            } else {
                *(uint4*)((__hip_bfloat16*)C0 + (size_t)(m0 + row) * N + n0 + ch * 8) = tv.u;
            }
        }
    }
}

// ---------------------------------------------------------------------------
// MFMA flash attention, S^T formulation (no P LDS round-trip).
// Grid (16, B*H) remapped so each XCD (n&7) owns 4 consecutive bh for all 16
// q-pairs (KV working set 2MB < 4MB XCD L2). Block does q-tiles j and 31-j.
// S^T = mfma(kf, qf): lane holds S[q = q0+w*16+(lane&15)][k = 16*t2+4*quad+r]
// -> softmax is per-lane-row; P values sit exactly in A-frag positions for
// PV mfmas over 16-wide k blocks (upper K half zero-padded, both operands).
// K/V staged via swizzled global_load_lds (slot chunk = idx ^ row-key).
// ---------------------------------------------------------------------------
__global__ __launch_bounds__(256)
void attn_mfma(const __hip_bfloat16* __restrict__ QKV, const __hip_bfloat16* __restrict__ Vt,
               __hip_bfloat16* __restrict__ Y) {
    __shared__ __align__(16) __hip_bfloat16 Ks[128 * 32];
    __shared__ __align__(16) __hip_bfloat16 VTS[96 * 128];
    const int tid = threadIdx.x;
    const int lane = tid & 63;
    const int w = tid >> 6;
    const int c = lane & 15;
    const int quad = lane >> 4;
    // XCD-locality swizzle
    const int nlin = blockIdx.y * 16 + blockIdx.x;
    const int x8 = nlin & 7, mm = nlin >> 3;
    const int bh = x8 * 4 + (mm >> 4);
    const int qpair = mm & 15;
    const int b = bh >> 4, h = bh & 15;
    const size_t qbase = (size_t)b * T_ * QS_ + h * 32;
    const size_t kbase = qbase + 512;
    const size_t vtbase = (size_t)bh * 96 * T_;
    const size_t ybase = (size_t)b * T_ * DM_ + h * 96;
    const float scale2 = 0.17677669529663687f * 1.4426950408889634f;  // /sqrt(32)*log2(e)

    for (int half = 0; half < 2; ++half) {
        const int qt = half ? (31 - qpair) : qpair;
        const int q0 = qt * 64;
        const int ntiles = (qt >> 1) + 1;
        const int qrow = q0 + w * 16 + c;
        const bf16x8_t qf = *(const bf16x8_t*)(QKV + qbase + (size_t)qrow * QS_ + quad * 8);

        f32x4_t o[6] = {};
        float mrow = -1e30f, lrow = 0.f;

        for (int t = 0; t < ntiles; ++t) {
            const int k0 = t * 128;
#pragma unroll
            for (int p = 0; p < 2; ++p) {     // K tile: 128 rows x 4 chunks
                const int s = p * 256 + tid;
                const int row = s >> 2;
                const int ch = (s & 3) ^ ((row >> 1) & 3);
                __builtin_amdgcn_global_load_lds(
                    GPTR(QKV + kbase + (size_t)(k0 + row) * QS_ + ch * 8),
                    LPTR(Ks + s * 8), 16, 0, 0);
            }
#pragma unroll
            for (int p = 0; p < 6; ++p) {     // V^T tile: 96 rows x 16 chunks
                const int s = p * 256 + tid;
                const int vr = s >> 4;
                const int ch = (s & 15) ^ (vr & 15);
                __builtin_amdgcn_global_load_lds(
                    GPTR(Vt + vtbase + (size_t)vr * T_ + k0 + ch * 8),
                    LPTR(VTS + s * 8), 16, 0, 0);
            }
            __syncthreads();

            f32x4_t s[8];
#pragma unroll
            for (int t2 = 0; t2 < 8; ++t2) {
                const int krow = t2 * 16 + c;
                const bf16x8_t kf =
                    *(const bf16x8_t*)(Ks + (krow * 4 + (quad ^ ((krow >> 1) & 3))) * 8);
                f32x4_t z = {0.f, 0.f, 0.f, 0.f};
                s[t2] = __builtin_amdgcn_mfma_f32_16x16x32_bf16(kf, qf, z, 0, 0, 0);
            }

            float p[8][4];
            if (k0 + 128 > q0) {
#pragma unroll
                for (int t2 = 0; t2 < 8; ++t2) {
                    const int kk = k0 + t2 * 16 + quad * 4;
#pragma unroll
                    for (int r = 0; r < 4; ++r) {
                        float v = s[t2][r] * scale2;
                        if (kk + r > qrow) v = -1e30f;
                        p[t2][r] = v;
                    }
                }
            } else {
#pragma unroll
                for (int t2 = 0; t2 < 8; ++t2)
#pragma unroll
                    for (int r = 0; r < 4; ++r) p[t2][r] = s[t2][r] * scale2;
            }

            // online softmax: one q-row per lane, cols spread over quads
            float mx = p[0][0];
#pragma unroll
            for (int t2 = 0; t2 < 8; ++t2)
#pragma unroll
                for (int r = 0; r < 4; ++r) mx = fmaxf(mx, p[t2][r]);
            mx = fmaxf(mx, __shfl_xor(mx, 16));
            mx = fmaxf(mx, __shfl_xor(mx, 32));
            const float mnew = fmaxf(mrow, mx);
            const float alpha = exp2f(mrow - mnew);
            mrow = mnew;
            float rsum = 0.f;
#pragma unroll
            for (int t2 = 0; t2 < 8; ++t2)
#pragma unroll
                for (int r = 0; r < 4; ++r) {
                    p[t2][r] = exp2f(p[t2][r] - mnew);
                    rsum += p[t2][r];
                }
            rsum += __shfl_xor(rsum, 16);
            rsum += __shfl_xor(rsum, 32);
            lrow = lrow * alpha + rsum;

            // rescale O: O rows live at q=quad*4+r, alpha lives at q=c
            float arow[4];
#pragma unroll
            for (int r = 0; r < 4; ++r) arow[r] = __shfl(alpha, quad * 20 + r);
#pragma unroll
            for (int nb = 0; nb < 6; ++nb)
#pragma unroll
                for (int r = 0; r < 4; ++r) o[nb][r] *= arow[r];

            // PV: P as A-frag, V^T as B-frag; upper K half zeroed on both
#pragma unroll
            for (int t2 = 0; t2 < 8; ++t2) {
                union { bf16x8_t v; __hip_bfloat16 h[8]; unsigned int u[4]; } au;
                au.u[2] = 0; au.u[3] = 0;
#pragma unroll
                for (int r = 0; r < 4; ++r) au.h[r] = __float2bfloat16(p[t2][r]);
#pragma unroll
                for (int nb = 0; nb < 6; ++nb) {
                    const int vr = nb * 16 + c;
                    const int slot = (2 * t2 + (quad >> 1)) ^ (vr & 15);
                    union { bf16x8_t v; unsigned int u[4]; } bu;
                    const uint2 vv = *(const uint2*)(VTS + (vr * 16 + slot) * 8 + (quad & 1) * 4);
                    bu.u[0] = vv.x; bu.u[1] = vv.y; bu.u[2] = 0; bu.u[3] = 0;
                    o[nb] = __builtin_amdgcn_mfma_f32_16x16x32_bf16(au.v, bu.v, o[nb], 0, 0, 0);
                }
            }
            __syncthreads();
        }

        const float linv = 1.f / lrow;
        float lr4[4];
#pragma unroll
        for (int r = 0; r < 4; ++r) lr4[r] = __shfl(linv, quad * 20 + r);
#pragma unroll
        for (int r = 0; r < 4; ++r) {
            const size_t rowoff = ybase + (size_t)(q0 + w * 16 + quad * 4 + r) * DM_;
#pragma unroll
            for (int nb = 0; nb < 6; ++nb)
                Y[rowoff + nb * 16 + c] = __float2bfloat16(o[nb][r] * lr4[r]);
        }
    }
}

// ---------------------------------------------------------------------------
// Workspace map (99 MB; phase-aliased, lifetimes stream-ordered):
//   [  0,  5) wqkvT   [ 5, 8) woT   [ 8,18) wewgT (weT 8..16 | wgT 16..18)
//   [ 18,26) wuT   [26,34) wcT   [34, +16K) bqkv   [+16K, +64K) bewg
//   [ 35,43) x1b -> x2b
//   [ 43,63) qkv -> xmid fp32 (43..59)
//   [ 63,75) vt    [75,87) yb
//   [ 59,91) eb (vt/yb dead by then; EPI4 in-place)   [91,99) hb
// ---------------------------------------------------------------------------
extern "C" void kernel_launch(void* const* d_in, const int* in_sizes, int n_in,
                              void* d_out, int out_size, void* d_ws, size_t ws_size,
                              hipStream_t stream) {
    const float* x     = (const float*)d_in[0];
    const float* ln1_w = (const float*)d_in[2];
    const float* ln1_b = (const float*)d_in[3];
    const float* wq = (const float*)d_in[4];  const float* bq = (const float*)d_in[5];
    const float* wk = (const float*)d_in[6];  const float* bk = (const float*)d_in[7];
    const float* wv = (const float*)d_in[8];  const float* bv = (const float*)d_in[9];
    const float* wo = (const float*)d_in[10]; const float* bo = (const float*)d_in[11];
    const float* ln2_w = (const float*)d_in[12];
    const float* ln2_b = (const float*)d_in[13];
    const float* we = (const float*)d_in[14]; const float* be = (const float*)d_in[15];
    const float* wg = (const float*)d_in[16]; const float* bg = (const float*)d_in[17];
    const float* wu = (const float*)d_in[18]; const float* bu = (const float*)d_in[19];
    const float* wc = (const float*)d_in[20]; const float* bc = (const float*)d_in[21];
    float* out = (float*)d_out;

    char* ws = (char*)d_ws;
    typedef __hip_bfloat16 bf16;
    bf16* wqkvT = (bf16*)(ws + (size_t) 0 * MB);
    bf16* wqT   = wqkvT;
    bf16* wkT   = (bf16*)(ws + (size_t) 1 * MB);
    bf16* wvT   = (bf16*)(ws + (size_t) 2 * MB);
    bf16* woT   = (bf16*)(ws + (size_t) 5 * MB);
    bf16* wewgT = (bf16*)(ws + (size_t) 8 * MB);
    bf16* weT   = wewgT;
    bf16* wgT   = (bf16*)(ws + (size_t)16 * MB);
    bf16* wuT   = (bf16*)(ws + (size_t)18 * MB);
    bf16* wcT   = (bf16*)(ws + (size_t)26 * MB);
    float* bqkv = (float*)(ws + (size_t)34 * MB);
    float* bewg = (float*)(ws + (size_t)34 * MB + 65536);
    bf16* x1b   = (bf16*)(ws + (size_t)35 * MB);
    bf16* x2b   = x1b;
    bf16* qkv   = (bf16*)(ws + (size_t)43 * MB);
    float* xmid = (float*)(ws + (size_t)43 * MB);
    bf16* vt    = (bf16*)(ws + (size_t)63 * MB);
    bf16* yb    = (bf16*)(ws + (size_t)75 * MB);
    bf16* eb    = (bf16*)(ws + (size_t)59 * MB);
    bf16* hb    = (bf16*)(ws + (size_t)91 * MB);

    // batched weight transposes (tile counts: 512,512,1536,1536,4096,1024,4096,4096)
    TCTab tab;
    tab.src[0] = wq; tab.dst[0] = wqT; tab.K[0] = D_;  tab.N[0] = DC_; tab.off[0] = 0;
    tab.src[1] = wk; tab.dst[1] = wkT; tab.K[1] = D_;  tab.N[1] = DC_; tab.off[1] = 512;
    tab.src[2] = wv; tab.dst[2] = wvT; tab.K[2] = D_;  tab.N[2] = DM_; tab.off[2] = 1024;
    tab.src[3] = wo; tab.dst[3] = woT; tab.K[3] = DM_; tab.N[3] = D_;  tab.off[3] = 2560;
    tab.src[4] = we; tab.dst[4] = weT; tab.K[4] = D_;  tab.N[4] = DE_; tab.off[4] = 4096;
    tab.src[5] = wg; tab.dst[5] = wgT; tab.K[5] = D_;  tab.N[5] = DG_; tab.off[5] = 8192;
    tab.src[6] = wu; tab.dst[6] = wuT; tab.K[6] = DG_; tab.N[6] = DE_; tab.off[6] = 9216;
    tab.src[7] = wc; tab.dst[7] = wcT; tab.K[7] = DE_; tab.N[7] = D_;  tab.off[7] = 13312;
    transpose_cast_all<<<17408, dim3(32, 8), 0, stream>>>(tab);
    concat_bias3<<<(QS_ + 255) / 256, 256, 0, stream>>>(bq, 512, bk, 512, bv, QS_, bqkv);
    concat_bias3<<<(EG_ + 255) / 256, 256, 0, stream>>>(be, DE_, bg, DG_, nullptr, EG_, bewg);

    ln_cast<<<ROWS, 256, 0, stream>>>(x, ln1_w, ln1_b, x1b);

    gemm_bt<0, 128, 128><<<dim3(QS_ / 128, ROWS / 128), 256, 0, stream>>>(
        x1b, wqkvT, bqkv, nullptr, nullptr, qkv, nullptr, ROWS, QS_, D_);

    transpose_v<<<dim3(T_ / 32, 3, B_ * H_), dim3(32, 8), 0, stream>>>(qkv, vt);

    attn_mfma<<<dim3(16, B_ * H_), 256, 0, stream>>>(qkv, vt, yb);

    gemm_bt<1, 64, 64><<<dim3(D_ / 64, ROWS / 64), 256, 0, stream>>>(
        yb, woT, bo, x, nullptr, xmid, nullptr, ROWS, D_, DM_);

    ln_cast<<<ROWS, 256, 0, stream>>>(xmid, ln2_w, ln2_b, x2b);

    gemm_bt<5, 128, 128><<<dim3(EG_ / 128, ROWS / 128), 256, 0, stream>>>(
        x2b, wewgT, bewg, nullptr, nullptr, eb, hb, ROWS, EG_, D_);

    gemm_bt<4, 128, 128><<<dim3(DE_ / 128, ROWS / 128), 256, 0, stream>>>(
        hb, wuT, bu, nullptr, eb, eb, nullptr, ROWS, DE_, DG_);

    gemm_bt<1, 64, 64><<<dim3(D_ / 64, ROWS / 64), 256, 0, stream>>>(
        eb, wcT, bc, xmid, nullptr, out, nullptr, ROWS, D_, DE_);
}